// Round 10
// baseline (87.323 us; speedup 1.0000x reference)
//
#include <hip/hip_runtime.h>
#include <hip/hip_bf16.h>

typedef __bf16 bf16_t;
typedef __bf16 bf16x8 __attribute__((ext_vector_type(8)));
typedef float  f32x4  __attribute__((ext_vector_type(4)));

#define M_ROWS 12544   // 64*14*14
#define K_DIM  512
#define N_DIM  2048
#define BM 128
#define BN 128
#define BK 64
#define KSTEPS (K_DIM / BK)        // 8
#define TILES_M (M_ROWS / BM)      // 98
#define TILES_N (N_DIM / BN)       // 16
#define NBLK (TILES_M * TILES_N)   // 1568 (divisible by 8)

// ---------------- Kernel 1: residual add + LayerNorm -> bf16 ----------------
__global__ __launch_bounds__(256) void add_ln_bf16(
    const float* __restrict__ xa, const float* __restrict__ xb,
    const float* __restrict__ gamma, const float* __restrict__ beta,
    bf16_t* __restrict__ xn)
{
    const int wave = threadIdx.x >> 6;
    const int lane = threadIdx.x & 63;
    const int row  = blockIdx.x * 4 + wave;
    const size_t base = (size_t)row * K_DIM + lane * 8;

    float4 a0 = *(const float4*)(xa + base);
    float4 a1 = *(const float4*)(xa + base + 4);
    float4 b0 = *(const float4*)(xb + base);
    float4 b1 = *(const float4*)(xb + base + 4);

    float v[8] = {a0.x + b0.x, a0.y + b0.y, a0.z + b0.z, a0.w + b0.w,
                  a1.x + b1.x, a1.y + b1.y, a1.z + b1.z, a1.w + b1.w};
    float s = 0.f, sq = 0.f;
#pragma unroll
    for (int j = 0; j < 8; ++j) { s += v[j]; sq += v[j] * v[j]; }
#pragma unroll
    for (int off = 32; off >= 1; off >>= 1) {
        s  += __shfl_xor(s, off, 64);
        sq += __shfl_xor(sq, off, 64);
    }
    const float mean = s * (1.0f / 512.0f);
    const float var  = sq * (1.0f / 512.0f) - mean * mean;
    const float rstd = rsqrtf(var + 1e-5f);

    float4 g0  = *(const float4*)(gamma + lane * 8);
    float4 g1  = *(const float4*)(gamma + lane * 8 + 4);
    float4 be0 = *(const float4*)(beta  + lane * 8);
    float4 be1 = *(const float4*)(beta  + lane * 8 + 4);
    float g[8]  = {g0.x, g0.y, g0.z, g0.w, g1.x, g1.y, g1.z, g1.w};
    float bt[8] = {be0.x, be0.y, be0.z, be0.w, be1.x, be1.y, be1.z, be1.w};

    bf16x8 o;
#pragma unroll
    for (int j = 0; j < 8; ++j)
        o[j] = (bf16_t)((v[j] - mean) * rstd * g[j] + bt[j]);
    *(bf16x8*)(xn + base) = o;
}

// ---------------- Kernel 2: W [512][2048] f32 -> Wt [2048][512] bf16 --------
__global__ __launch_bounds__(256) void wt_bf16(
    const float* __restrict__ W, bf16_t* __restrict__ Wt)
{
    __shared__ float t[32][33];
    const int bk = blockIdx.x & 15;
    const int bn = blockIdx.x >> 4;
    const int tx = threadIdx.x & 31;
    const int ty = threadIdx.x >> 5;
#pragma unroll
    for (int r = 0; r < 4; ++r) {
        int k = bk * 32 + ty + r * 8;
        t[ty + r * 8][tx] = W[(size_t)k * N_DIM + bn * 32 + tx];
    }
    __syncthreads();
#pragma unroll
    for (int r = 0; r < 4; ++r) {
        int n = bn * 32 + ty + r * 8;
        Wt[(size_t)n * K_DIM + bk * 32 + tx] = (bf16_t)t[tx][ty + r * 8];
    }
}

// ---------------- Kernel 3: bf16 MFMA GEMM + bias + exact GELU --------------
__device__ __forceinline__ void gload_lds16(const bf16_t* g, bf16_t* l) {
    __builtin_amdgcn_global_load_lds(
        (const __attribute__((address_space(1))) void*)g,
        (__attribute__((address_space(3))) void*)l, 16, 0, 0);
}

// Branchless exact-GELU: erf via Abramowitz-Stegun 7.1.26 (|err| < ~2e-7)
__device__ __forceinline__ float gelu_f(float x) {
    const float y = fabsf(x) * 0.70710678118654752f;
    const float t = __builtin_amdgcn_rcpf(__builtin_fmaf(0.3275911f, y, 1.0f));
    float p = __builtin_fmaf(1.061405429f, t, -1.453152027f);
    p = __builtin_fmaf(p, t, 1.421413741f);
    p = __builtin_fmaf(p, t, -0.284496736f);
    p = __builtin_fmaf(p, t, 0.254829592f);
    p = p * t;
    const float e = __expf(-y * y);
    float er = __builtin_fmaf(-p, e, 1.0f);   // erf(|x|/sqrt2)
    er = __builtin_copysignf(er, x);
    return 0.5f * x * (1.0f + er);
}

// 128x128 tile, 4 waves (2x2), BK=64. A staged in LDS (double-buffered,
// 32 KB, XOR-swizzled both-sides per rule #21). B fragments loaded DIRECTLY
// global->VGPR from the L2-hot W^T (2 MB) — halves LDS-pipe traffic, which
// per-pipe arithmetic says was the saturated resource (~72% occupancy)
// common to all four prior schedule variants.
// vmcnt gates rely on in-order vmcnt retirement (m135): ops newer than
// A-stage(t) = B-prefetch(t)[8] + A-stage(t+1)[4] => vmcnt(12) drains A(t).
__global__ __launch_bounds__(256) void gemm_bias_gelu(
    const bf16_t* __restrict__ A,   // [M_ROWS][K_DIM] bf16
    const bf16_t* __restrict__ Bt,  // [N_DIM][K_DIM]  bf16 (W^T)
    const float* __restrict__ bias, // [N_DIM]
    float* __restrict__ out)        // [M_ROWS][N_DIM] f32
{
    __shared__ bf16_t As[2][BM * BK];   // 2 x 16 KB = 32 KB total

    const int bid = blockIdx.x;
    const int wg  = (bid & 7) * (NBLK / 8) + (bid >> 3);   // XCD-chunked, bijective
    const int tm  = wg >> 4;
    const int tn  = wg & 15;            // tn-fast: B stripe stays L2-hot

    const int tid  = threadIdx.x;
    const int wave = tid >> 6;
    const int lane = tid & 63;
    const int wr = wave >> 1;
    const int wc = wave & 1;

    const bf16_t* Ab = A  + (size_t)tm * BM * K_DIM;
    const bf16_t* Bb = Bt + (size_t)tn * BN * K_DIM;

    // A staging: seg = 8 rows x 64 k = 1024 B = 64 lanes x 16 B
    const int srow = lane >> 3;                 // 0..7 row within segment
    const int jsrc = (lane & 7) ^ srow;         // inverse-swizzled 16B chunk

    f32x4 acc[4][4];
#pragma unroll
    for (int m = 0; m < 4; ++m)
#pragma unroll
        for (int n = 0; n < 4; ++n)
            acc[m][n] = (f32x4){0.f, 0.f, 0.f, 0.f};

    auto stageA = [&](int buf, int k0) {
#pragma unroll
        for (int c = 0; c < 4; ++c) {
            const int seg = wave * 4 + c;       // 0..15, wave-uniform LDS base
            const int row = seg * 8 + srow;
            gload_lds16(Ab + (size_t)row * K_DIM + k0 + jsrc * 8, &As[buf][seg * 512]);
        }
    };

    // B fragment loads: same index math as the old ds_read, but from global.
    // One dwordx4 per (n,kk): 16 rows x 64 contiguous bytes -> L1/L2 friendly.
    auto loadB = [&](int k0, bf16x8 (&b)[4][2]) {
#pragma unroll
        for (int n = 0; n < 4; ++n)
#pragma unroll
            for (int kk = 0; kk < 2; ++kk) {
                const int r = wc * 64 + n * 16 + (lane & 15);
                const int j = kk * 4 + (lane >> 4);
                b[n][kk] = *(const bf16x8*)(Bb + (size_t)r * K_DIM + k0 + j * 8);
            }
    };

    bf16x8 bA[4][2], bB[4][2];   // double-buffered B fragments (static idx)

    stageA(0, 0);                // A(0): 4 loads
    loadB(0, bA);                // B(0): 8 loads

#pragma unroll
    for (int t = 0; t < KSTEPS; ++t) {
        const int cur = t & 1;
        if (t < KSTEPS - 1) {
            stageA(cur ^ 1, (t + 1) * BK);                    // A(t+1): 4 loads
            // newer-than-A(t) = B(t)[8] + A(t+1)[4] = 12 (in-order retire)
            asm volatile("s_waitcnt vmcnt(12)" ::: "memory");
        } else {
            // newer-than-A(7) = B(7)[8]
            asm volatile("s_waitcnt vmcnt(8)" ::: "memory");
        }
        __builtin_amdgcn_s_barrier();

        // prefetch next tile's B frags; latency hides under this tile's MFMA
        if (t < KSTEPS - 1) {
            if (t & 1) loadB((t + 1) * BK, bA);
            else       loadB((t + 1) * BK, bB);
        }

        bf16x8 af[4][2];
#pragma unroll
        for (int m = 0; m < 4; ++m)
#pragma unroll
            for (int kk = 0; kk < 2; ++kk) {
                const int r = wr * 64 + m * 16 + (lane & 15);
                const int j = kk * 4 + (lane >> 4);
                af[m][kk] = *(const bf16x8*)(&As[cur][r * BK + ((j ^ (r & 7)) << 3)]);
            }

        __builtin_amdgcn_s_setprio(1);
        if (t & 1) {
#pragma unroll
            for (int kk = 0; kk < 2; ++kk)
#pragma unroll
                for (int m = 0; m < 4; ++m)
#pragma unroll
                    for (int n = 0; n < 4; ++n)
                        acc[m][n] = __builtin_amdgcn_mfma_f32_16x16x32_bf16(
                            af[m][kk], bB[n][kk], acc[m][n], 0, 0, 0);
        } else {
#pragma unroll
            for (int kk = 0; kk < 2; ++kk)
#pragma unroll
                for (int m = 0; m < 4; ++m)
#pragma unroll
                    for (int n = 0; n < 4; ++n)
                        acc[m][n] = __builtin_amdgcn_mfma_f32_16x16x32_bf16(
                            af[m][kk], bA[n][kk], acc[m][n], 0, 0, 0);
        }
        __builtin_amdgcn_s_setprio(0);

        if (t < KSTEPS - 1) __builtin_amdgcn_s_barrier();  // A reads done before restage
    }

    // Epilogue: bias + exact GELU, nontemporal stores.
    // C/D layout: col = lane&15, row = (lane>>4)*4 + reg.
    const int rbase = tm * BM + wr * 64;
    const int cbase = tn * BN + wc * 64;
#pragma unroll
    for (int n = 0; n < 4; ++n) {
        const int col = cbase + n * 16 + (lane & 15);
        const float bv = bias[col];
#pragma unroll
        for (int m = 0; m < 4; ++m) {
            const int row0 = rbase + m * 16 + (lane >> 4) * 4;
#pragma unroll
            for (int i = 0; i < 4; ++i) {
                const float x = acc[m][n][i] + bv;
                __builtin_nontemporal_store(gelu_f(x),
                    out + (size_t)(row0 + i) * N_DIM + col);
            }
        }
    }
}

extern "C" void kernel_launch(void* const* d_in, const int* in_sizes, int n_in,
                              void* d_out, int out_size, void* d_ws, size_t ws_size,
                              hipStream_t stream)
{
    const float* x203  = (const float*)d_in[0];
    const float* x217  = (const float*)d_in[1];
    const float* gamma = (const float*)d_in[2];
    const float* beta  = (const float*)d_in[3];
    const float* W     = (const float*)d_in[4];
    const float* bias  = (const float*)d_in[5];
    float* out = (float*)d_out;

    bf16_t* xn = (bf16_t*)d_ws;
    bf16_t* Wt = (bf16_t*)((char*)d_ws + (size_t)M_ROWS * K_DIM * sizeof(bf16_t));

    add_ln_bf16<<<M_ROWS / 4, 256, 0, stream>>>(x203, x217, gamma, beta, xn);
    wt_bf16<<<(K_DIM / 32) * (N_DIM / 32), 256, 0, stream>>>(W, Wt);
    gemm_bias_gelu<<<NBLK, 256, 0, stream>>>(xn, Wt, bias, out);
}

// Round 11
// 74.935 us; speedup vs baseline: 1.1653x; 1.1653x over previous
//
#include <hip/hip_runtime.h>
#include <hip/hip_bf16.h>

typedef __bf16 bf16_t;
typedef __bf16 bf16x8 __attribute__((ext_vector_type(8)));
typedef float  f32x4  __attribute__((ext_vector_type(4)));

#define M_ROWS 12544   // 64*14*14
#define K_DIM  512
#define N_DIM  2048
#define BM 128
#define BN 128
#define BK 64
#define KSTEPS (K_DIM / BK)        // 8
#define TILES_M (M_ROWS / BM)      // 98
#define TILES_N (N_DIM / BN)       // 16
#define NTILES (TILES_M * TILES_N) // 1568
#define GRID 512                   // 2 persistent blocks per CU

// ---------------- Kernel 1: residual add + LayerNorm -> bf16 ----------------
__global__ __launch_bounds__(256) void add_ln_bf16(
    const float* __restrict__ xa, const float* __restrict__ xb,
    const float* __restrict__ gamma, const float* __restrict__ beta,
    bf16_t* __restrict__ xn)
{
    const int wave = threadIdx.x >> 6;
    const int lane = threadIdx.x & 63;
    const int row  = blockIdx.x * 4 + wave;
    const size_t base = (size_t)row * K_DIM + lane * 8;

    float4 a0 = *(const float4*)(xa + base);
    float4 a1 = *(const float4*)(xa + base + 4);
    float4 b0 = *(const float4*)(xb + base);
    float4 b1 = *(const float4*)(xb + base + 4);

    float v[8] = {a0.x + b0.x, a0.y + b0.y, a0.z + b0.z, a0.w + b0.w,
                  a1.x + b1.x, a1.y + b1.y, a1.z + b1.z, a1.w + b1.w};
    float s = 0.f, sq = 0.f;
#pragma unroll
    for (int j = 0; j < 8; ++j) { s += v[j]; sq += v[j] * v[j]; }
#pragma unroll
    for (int off = 32; off >= 1; off >>= 1) {
        s  += __shfl_xor(s, off, 64);
        sq += __shfl_xor(sq, off, 64);
    }
    const float mean = s * (1.0f / 512.0f);
    const float var  = sq * (1.0f / 512.0f) - mean * mean;
    const float rstd = rsqrtf(var + 1e-5f);

    float4 g0  = *(const float4*)(gamma + lane * 8);
    float4 g1  = *(const float4*)(gamma + lane * 8 + 4);
    float4 be0 = *(const float4*)(beta  + lane * 8);
    float4 be1 = *(const float4*)(beta  + lane * 8 + 4);
    float g[8]  = {g0.x, g0.y, g0.z, g0.w, g1.x, g1.y, g1.z, g1.w};
    float bt[8] = {be0.x, be0.y, be0.z, be0.w, be1.x, be1.y, be1.z, be1.w};

    bf16x8 o;
#pragma unroll
    for (int j = 0; j < 8; ++j)
        o[j] = (bf16_t)((v[j] - mean) * rstd * g[j] + bt[j]);
    *(bf16x8*)(xn + base) = o;
}

// ---------------- Kernel 2: W [512][2048] f32 -> Wt [2048][512] bf16 --------
__global__ __launch_bounds__(256) void wt_bf16(
    const float* __restrict__ W, bf16_t* __restrict__ Wt)
{
    __shared__ float t[32][33];
    const int bk = blockIdx.x & 15;
    const int bn = blockIdx.x >> 4;
    const int tx = threadIdx.x & 31;
    const int ty = threadIdx.x >> 5;
#pragma unroll
    for (int r = 0; r < 4; ++r) {
        int k = bk * 32 + ty + r * 8;
        t[ty + r * 8][tx] = W[(size_t)k * N_DIM + bn * 32 + tx];
    }
    __syncthreads();
#pragma unroll
    for (int r = 0; r < 4; ++r) {
        int n = bn * 32 + ty + r * 8;
        Wt[(size_t)n * K_DIM + bk * 32 + tx] = (bf16_t)t[tx][ty + r * 8];
    }
}

// ---------------- Kernel 3: persistent MFMA GEMM + bias + exact GELU --------
__device__ __forceinline__ void gload_lds16(const bf16_t* g, bf16_t* l) {
    __builtin_amdgcn_global_load_lds(
        (const __attribute__((address_space(1))) void*)g,
        (__attribute__((address_space(3))) void*)l, 16, 0, 0);
}

// Branchless exact-GELU: erf via Abramowitz-Stegun 7.1.26 (|err| < ~2e-7)
__device__ __forceinline__ float gelu_f(float x) {
    const float y = fabsf(x) * 0.70710678118654752f;
    const float t = __builtin_amdgcn_rcpf(__builtin_fmaf(0.3275911f, y, 1.0f));
    float p = __builtin_fmaf(1.061405429f, t, -1.453152027f);
    p = __builtin_fmaf(p, t, 1.421413741f);
    p = __builtin_fmaf(p, t, -0.284496736f);
    p = __builtin_fmaf(p, t, 0.254829592f);
    p = p * t;
    const float e = __expf(-y * y);
    float er = __builtin_fmaf(-p, e, 1.0f);   // erf(|x|/sqrt2)
    er = __builtin_copysignf(er, x);
    return 0.5f * x * (1.0f + er);
}

// Persistent work-stealing GEMM. grid=512 (2 blocks/CU), each block loops
// over tiles from an atomic ticket counter. Cross-tile pipelining: at step
// t==7 of tile i, the block stages tile i+1's first K-buffer (ticket
// pre-grabbed at t==6 by thread 0 -> shared broadcast, 2 barriers before
// read), so next-tile loads fly under this tile's epilogue. Inner step =
// proven R4 recipe: stage(t+1) -> vmcnt(8) -> barrier -> ds_read+MFMA ->
// barrier, XOR swizzle chunk^(row&7) applied both sides (rule #21).
__global__ __launch_bounds__(256) void gemm_bias_gelu(
    const bf16_t* __restrict__ A,   // [M_ROWS][K_DIM] bf16
    const bf16_t* __restrict__ Bt,  // [N_DIM][K_DIM]  bf16 (W^T)
    const float* __restrict__ bias, // [N_DIM]
    float* __restrict__ out,        // [M_ROWS][N_DIM] f32
    int* __restrict__ cnt)          // ticket counter (zeroed on stream)
{
    __shared__ bf16_t As[2][BM * BK];   // 2 x 16 KB
    __shared__ bf16_t Bs[2][BN * BK];   // 2 x 16 KB -> 64 KB total
    __shared__ int sh_idx, sh_next;

    const int tid  = threadIdx.x;
    const int wave = tid >> 6;
    const int lane = tid & 63;
    const int wr = wave >> 1;
    const int wc = wave & 1;

    // staging: seg = 8 rows x 64 k = 1024 B = 64 lanes x 16 B
    const int srow = lane >> 3;                 // 0..7 row within segment
    const int jsrc = (lane & 7) ^ srow;         // inverse-swizzled 16B chunk

    auto stage = [&](int buf, int k0, const bf16_t* Ab, const bf16_t* Bb) {
#pragma unroll
        for (int c = 0; c < 4; ++c) {
            const int seg = wave * 4 + c;       // wave-uniform LDS base
            const int row = seg * 8 + srow;
            gload_lds16(Ab + (size_t)row * K_DIM + k0 + jsrc * 8, &As[buf][seg * 512]);
            gload_lds16(Bb + (size_t)row * K_DIM + k0 + jsrc * 8, &Bs[buf][seg * 512]);
        }
    };

    if (tid == 0) sh_idx = atomicAdd(cnt, 1);
    __syncthreads();
    int idx = sh_idx;
    if (idx >= NTILES) return;

    const bf16_t* Ab = A  + (size_t)(idx >> 4) * BM * K_DIM;  // tm = idx>>4
    const bf16_t* Bb = Bt + (size_t)(idx & 15) * BN * K_DIM;  // tn = idx&15 (tn-fast)
    const bf16_t* nAb = Ab; const bf16_t* nBb = Bb;
    int nidx = idx;

    stage(0, 0, Ab, Bb);   // first tile prologue (8 loads in flight)

    f32x4 acc[4][4];
#pragma unroll
    for (int m = 0; m < 4; ++m)
#pragma unroll
        for (int n = 0; n < 4; ++n)
            acc[m][n] = (f32x4){0.f, 0.f, 0.f, 0.f};

    for (;;) {
#pragma unroll
        for (int t = 0; t < KSTEPS; ++t) {
            const int cur = t & 1;

            if (t == 6 && tid == 0) sh_next = atomicAdd(cnt, 1);  // pre-grab

            if (t < KSTEPS - 1) {
                stage(cur ^ 1, (t + 1) * BK, Ab, Bb);            // +8 loads
                asm volatile("s_waitcnt vmcnt(8)" ::: "memory"); // step t landed
            } else {
                nidx = sh_next;                  // written at t==6, 2 barriers ago
                if (nidx < NTILES) {
                    nAb = A  + (size_t)(nidx >> 4) * BM * K_DIM;
                    nBb = Bt + (size_t)(nidx & 15) * BN * K_DIM;
                    stage(0, 0, nAb, nBb);       // next tile's step 0 -> buf0
                    asm volatile("s_waitcnt vmcnt(8)" ::: "memory");
                } else {
                    asm volatile("s_waitcnt vmcnt(0)" ::: "memory");
                }
            }
            __builtin_amdgcn_s_barrier();

            bf16x8 af[4], bfr[4];
            const int j = lane >> 4;  // combined with kk below
#pragma unroll
            for (int kk = 0; kk < 2; ++kk) {
                const int jj = kk * 4 + j;       // 16B k-slot 0..7
#pragma unroll
                for (int m = 0; m < 4; ++m) {
                    const int r = wr * 64 + m * 16 + (lane & 15);
                    af[m] = *(const bf16x8*)(&As[cur][r * BK + ((jj ^ (r & 7)) << 3)]);
                }
#pragma unroll
                for (int n = 0; n < 4; ++n) {
                    const int r = wc * 64 + n * 16 + (lane & 15);
                    bfr[n] = *(const bf16x8*)(&Bs[cur][r * BK + ((jj ^ (r & 7)) << 3)]);
                }
                __builtin_amdgcn_s_setprio(1);
#pragma unroll
                for (int m = 0; m < 4; ++m)
#pragma unroll
                    for (int n = 0; n < 4; ++n)
                        acc[m][n] = __builtin_amdgcn_mfma_f32_16x16x32_bf16(
                            af[m], bfr[n], acc[m][n], 0, 0, 0);
                __builtin_amdgcn_s_setprio(0);
            }
            __builtin_amdgcn_s_barrier();        // reads done before restage
        }

        // Epilogue for tile idx — overlaps next tile's in-flight buf0 loads.
        // C/D layout: col = lane&15, row = (lane>>4)*4 + reg.
        {
            const int rbase = (idx >> 4) * BM + wr * 64;
            const int cbase = (idx & 15) * BN + wc * 64;
#pragma unroll
            for (int n = 0; n < 4; ++n) {
                const int col = cbase + n * 16 + (lane & 15);
                const float bv = bias[col];
#pragma unroll
                for (int m = 0; m < 4; ++m) {
                    const int row0 = rbase + m * 16 + (lane >> 4) * 4;
#pragma unroll
                    for (int i = 0; i < 4; ++i) {
                        const float x = acc[m][n][i] + bv;
                        __builtin_nontemporal_store(gelu_f(x),
                            out + (size_t)(row0 + i) * N_DIM + col);
                    }
                }
            }
        }

        if (nidx >= NTILES) break;
        idx = nidx; Ab = nAb; Bb = nBb;
#pragma unroll
        for (int m = 0; m < 4; ++m)
#pragma unroll
            for (int n = 0; n < 4; ++n)
                acc[m][n] = (f32x4){0.f, 0.f, 0.f, 0.f};
    }
}

extern "C" void kernel_launch(void* const* d_in, const int* in_sizes, int n_in,
                              void* d_out, int out_size, void* d_ws, size_t ws_size,
                              hipStream_t stream)
{
    const float* x203  = (const float*)d_in[0];
    const float* x217  = (const float*)d_in[1];
    const float* gamma = (const float*)d_in[2];
    const float* beta  = (const float*)d_in[3];
    const float* W     = (const float*)d_in[4];
    const float* bias  = (const float*)d_in[5];
    float* out = (float*)d_out;

    // ws layout: xn bf16 [12544][512] | Wt bf16 [2048][512] | ticket counter
    bf16_t* xn = (bf16_t*)d_ws;
    bf16_t* Wt = (bf16_t*)((char*)d_ws + (size_t)M_ROWS * K_DIM * sizeof(bf16_t));
    int* cnt = (int*)((char*)d_ws + (size_t)M_ROWS * K_DIM * sizeof(bf16_t)
                                  + (size_t)N_DIM * K_DIM * sizeof(bf16_t));

    hipMemsetAsync(cnt, 0, sizeof(int), stream);
    add_ln_bf16<<<M_ROWS / 4, 256, 0, stream>>>(x203, x217, gamma, beta, xn);
    wt_bf16<<<(K_DIM / 32) * (N_DIM / 32), 256, 0, stream>>>(W, Wt);
    gemm_bias_gelu<<<GRID, 256, 0, stream>>>(xn, Wt, bias, out, cnt);
}

// Round 12
// 70.688 us; speedup vs baseline: 1.2353x; 1.0601x over previous
//
#include <hip/hip_runtime.h>
#include <hip/hip_bf16.h>

typedef __bf16 bf16_t;
typedef __bf16 bf16x8 __attribute__((ext_vector_type(8)));
typedef float  f32x4  __attribute__((ext_vector_type(4)));

#define M_ROWS 12544   // 64*14*14
#define K_DIM  512
#define N_DIM  2048
#define BM 128
#define BN 128
#define BK 32
#define KSTEPS (K_DIM / BK)        // 16
#define TILES_M (M_ROWS / BM)      // 98
#define TILES_N (N_DIM / BN)       // 16
#define NBLK (TILES_M * TILES_N)   // 1568 (divisible by 8)

// ---------------- Kernel 1: residual add + LayerNorm -> bf16 ----------------
__global__ __launch_bounds__(256) void add_ln_bf16(
    const float* __restrict__ xa, const float* __restrict__ xb,
    const float* __restrict__ gamma, const float* __restrict__ beta,
    bf16_t* __restrict__ xn)
{
    const int wave = threadIdx.x >> 6;
    const int lane = threadIdx.x & 63;
    const int row  = blockIdx.x * 4 + wave;
    const size_t base = (size_t)row * K_DIM + lane * 8;

    float4 a0 = *(const float4*)(xa + base);
    float4 a1 = *(const float4*)(xa + base + 4);
    float4 b0 = *(const float4*)(xb + base);
    float4 b1 = *(const float4*)(xb + base + 4);

    float v[8] = {a0.x + b0.x, a0.y + b0.y, a0.z + b0.z, a0.w + b0.w,
                  a1.x + b1.x, a1.y + b1.y, a1.z + b1.z, a1.w + b1.w};
    float s = 0.f, sq = 0.f;
#pragma unroll
    for (int j = 0; j < 8; ++j) { s += v[j]; sq += v[j] * v[j]; }
#pragma unroll
    for (int off = 32; off >= 1; off >>= 1) {
        s  += __shfl_xor(s, off, 64);
        sq += __shfl_xor(sq, off, 64);
    }
    const float mean = s * (1.0f / 512.0f);
    const float var  = sq * (1.0f / 512.0f) - mean * mean;
    const float rstd = rsqrtf(var + 1e-5f);

    float4 g0  = *(const float4*)(gamma + lane * 8);
    float4 g1  = *(const float4*)(gamma + lane * 8 + 4);
    float4 be0 = *(const float4*)(beta  + lane * 8);
    float4 be1 = *(const float4*)(beta  + lane * 8 + 4);
    float g[8]  = {g0.x, g0.y, g0.z, g0.w, g1.x, g1.y, g1.z, g1.w};
    float bt[8] = {be0.x, be0.y, be0.z, be0.w, be1.x, be1.y, be1.z, be1.w};

    bf16x8 o;
#pragma unroll
    for (int j = 0; j < 8; ++j)
        o[j] = (bf16_t)((v[j] - mean) * rstd * g[j] + bt[j]);
    *(bf16x8*)(xn + base) = o;
}

// ---------------- Kernel 2: W [512][2048] f32 -> Wt [2048][512] bf16 --------
__global__ __launch_bounds__(256) void wt_bf16(
    const float* __restrict__ W, bf16_t* __restrict__ Wt)
{
    __shared__ float t[32][33];
    const int bk = blockIdx.x & 15;
    const int bn = blockIdx.x >> 4;
    const int tx = threadIdx.x & 31;
    const int ty = threadIdx.x >> 5;
#pragma unroll
    for (int r = 0; r < 4; ++r) {
        int k = bk * 32 + ty + r * 8;
        t[ty + r * 8][tx] = W[(size_t)k * N_DIM + bn * 32 + tx];
    }
    __syncthreads();
#pragma unroll
    for (int r = 0; r < 4; ++r) {
        int n = bn * 32 + ty + r * 8;
        Wt[(size_t)n * K_DIM + bk * 32 + tx] = (bf16_t)t[tx][ty + r * 8];
    }
}

// ---------------- Kernel 3: bf16 MFMA GEMM + bias + exact GELU --------------
__device__ __forceinline__ void gload_lds16(const bf16_t* g, bf16_t* l) {
    __builtin_amdgcn_global_load_lds(
        (const __attribute__((address_space(1))) void*)g,
        (__attribute__((address_space(3))) void*)l, 16, 0, 0);
}

// Branchless exact-GELU: erf via Abramowitz-Stegun 7.1.26 (|err| < ~2e-7)
__device__ __forceinline__ float gelu_f(float x) {
    const float y = fabsf(x) * 0.70710678118654752f;
    const float t = __builtin_amdgcn_rcpf(__builtin_fmaf(0.3275911f, y, 1.0f));
    float p = __builtin_fmaf(1.061405429f, t, -1.453152027f);
    p = __builtin_fmaf(p, t, 1.421413741f);
    p = __builtin_fmaf(p, t, -0.284496736f);
    p = __builtin_fmaf(p, t, 0.254829592f);
    p = p * t;
    const float e = __expf(-y * y);
    float er = __builtin_fmaf(-p, e, 1.0f);   // erf(|x|/sqrt2)
    er = __builtin_copysignf(er, x);
    return 0.5f * x * (1.0f + er);
}

// 128x128 tile, 4 waves (2x2), BK=32, TRIPLE-buffered LDS (48 KB) = depth-2
// prefetch: tile t+2's loads issue while tile t computes, so ~2 step-times
// (~600-900 cyc) cover the HBM latency the depth-1 variants stalled on.
// 3 blocks/CU (launch_bounds 256,3; LDS 48 KB*3 = 144 <= 160 KB) gives 12
// waves/CU to absorb residual stalls. Swizzle (R5-proven): write-side
// gsrc = (lane&3)^((lane>>3)&3) on per-lane global source (gload_lds writes
// LDS linearly), read-side slot = j^((row>>1)&3) — rule #21 both-sides.
// vmcnt per wave (4 loads/stage, in-order): mid-loop outstanding = tiles
// t,t+1,t+2 = 12 -> vmcnt(8) drains tile t; tail 4 -> 0.
__global__ __launch_bounds__(256, 3) void gemm_bias_gelu(
    const bf16_t* __restrict__ A,   // [M_ROWS][K_DIM] bf16
    const bf16_t* __restrict__ Bt,  // [N_DIM][K_DIM]  bf16 (W^T)
    const float* __restrict__ bias, // [N_DIM]
    float* __restrict__ out)        // [M_ROWS][N_DIM] f32
{
    __shared__ bf16_t As[3][BM * BK];   // 3 x 8 KB
    __shared__ bf16_t Bs[3][BN * BK];   // 3 x 8 KB -> 48 KB total

    // XCD-chunked bijective swizzle (1568 % 8 == 0), tn-fast: 16 consecutive
    // wgs share one A-panel and sweep all of B (2 MB bf16) -> L2-fit.
    const int bid = blockIdx.x;
    const int wg  = (bid & 7) * (NBLK / 8) + (bid >> 3);
    const int tm  = wg >> 4;
    const int tn  = wg & 15;

    const int tid  = threadIdx.x;
    const int wave = tid >> 6;
    const int lane = tid & 63;
    const int wr = wave >> 1;
    const int wc = wave & 1;

    const bf16_t* Ab = A  + (size_t)tm * BM * K_DIM;
    const bf16_t* Bb = Bt + (size_t)tn * BN * K_DIM;

    // staging: seg = 16 rows x 32 k = 1024 B = 64 lanes x 16 B
    const int srow = lane >> 2;                       // row within segment
    const int gsrc = (lane & 3) ^ ((lane >> 3) & 3);  // inverse-swizzled chunk

    f32x4 acc[4][4];
#pragma unroll
    for (int m = 0; m < 4; ++m)
#pragma unroll
        for (int n = 0; n < 4; ++n)
            acc[m][n] = (f32x4){0.f, 0.f, 0.f, 0.f};

    auto stage = [&](int buf, int k0) {
#pragma unroll
        for (int c = 0; c < 2; ++c) {
            const int seg = wave * 2 + c;             // 0..7, wave-uniform
            const int row = seg * 16 + srow;
            gload_lds16(Ab + (size_t)row * K_DIM + k0 + gsrc * 8, &As[buf][seg * 512]);
            gload_lds16(Bb + (size_t)row * K_DIM + k0 + gsrc * 8, &Bs[buf][seg * 512]);
        }
    };

    stage(0, 0);        // tile 0: 4 loads/wave
    stage(1, BK);       // tile 1: +4 -> 8 outstanding

#pragma unroll
    for (int t = 0; t < KSTEPS; ++t) {
        const int cur = t % 3;
        if (t + 2 < KSTEPS) {
            stage((t + 2) % 3, (t + 2) * BK);                // +4 -> 12
            asm volatile("s_waitcnt vmcnt(8)" ::: "memory"); // tile t landed
        } else if (t + 1 < KSTEPS) {
            asm volatile("s_waitcnt vmcnt(4)" ::: "memory"); // t = 14
        } else {
            asm volatile("s_waitcnt vmcnt(0)" ::: "memory"); // t = 15
        }
        __builtin_amdgcn_s_barrier();

        bf16x8 af[4], bfr[4];
        const int j = lane >> 4;                      // 16B k-chunk 0..3
#pragma unroll
        for (int m = 0; m < 4; ++m) {
            const int r = wr * 64 + m * 16 + (lane & 15);
            af[m] = *(const bf16x8*)(&As[cur][r * BK + ((j ^ ((r >> 1) & 3)) << 3)]);
        }
#pragma unroll
        for (int n = 0; n < 4; ++n) {
            const int r = wc * 64 + n * 16 + (lane & 15);
            bfr[n] = *(const bf16x8*)(&Bs[cur][r * BK + ((j ^ ((r >> 1) & 3)) << 3)]);
        }
        __builtin_amdgcn_s_setprio(1);
#pragma unroll
        for (int m = 0; m < 4; ++m)
#pragma unroll
            for (int n = 0; n < 4; ++n)
                acc[m][n] = __builtin_amdgcn_mfma_f32_16x16x32_bf16(
                    af[m], bfr[n], acc[m][n], 0, 0, 0);
        __builtin_amdgcn_s_setprio(0);

        if (t < KSTEPS - 1) __builtin_amdgcn_s_barrier();  // reads done before restage
    }

    // Epilogue: bias + exact GELU, nontemporal stores.
    // C/D layout: col = lane&15, row = (lane>>4)*4 + reg.
    const int rbase = tm * BM + wr * 64;
    const int cbase = tn * BN + wc * 64;
#pragma unroll
    for (int n = 0; n < 4; ++n) {
        const int col = cbase + n * 16 + (lane & 15);
        const float bv = bias[col];
#pragma unroll
        for (int m = 0; m < 4; ++m) {
            const int row0 = rbase + m * 16 + (lane >> 4) * 4;
#pragma unroll
            for (int i = 0; i < 4; ++i) {
                const float x = acc[m][n][i] + bv;
                __builtin_nontemporal_store(gelu_f(x),
                    out + (size_t)(row0 + i) * N_DIM + col);
            }
        }
    }
}

extern "C" void kernel_launch(void* const* d_in, const int* in_sizes, int n_in,
                              void* d_out, int out_size, void* d_ws, size_t ws_size,
                              hipStream_t stream)
{
    const float* x203  = (const float*)d_in[0];
    const float* x217  = (const float*)d_in[1];
    const float* gamma = (const float*)d_in[2];
    const float* beta  = (const float*)d_in[3];
    const float* W     = (const float*)d_in[4];
    const float* bias  = (const float*)d_in[5];
    float* out = (float*)d_out;

    bf16_t* xn = (bf16_t*)d_ws;
    bf16_t* Wt = (bf16_t*)((char*)d_ws + (size_t)M_ROWS * K_DIM * sizeof(bf16_t));

    add_ln_bf16<<<M_ROWS / 4, 256, 0, stream>>>(x203, x217, gamma, beta, xn);
    wt_bf16<<<(K_DIM / 32) * (N_DIM / 32), 256, 0, stream>>>(W, Wt);
    gemm_bias_gelu<<<NBLK, 256, 0, stream>>>(xn, Wt, bias, out);
}

// Round 13
// 69.449 us; speedup vs baseline: 1.2574x; 1.0178x over previous
//
#include <hip/hip_runtime.h>
#include <hip/hip_bf16.h>

typedef __bf16 bf16_t;
typedef __bf16 bf16x8 __attribute__((ext_vector_type(8)));
typedef float  f32x4  __attribute__((ext_vector_type(4)));

#define M_ROWS 12544   // 64*14*14
#define K_DIM  512
#define N_DIM  2048
#define BM 128
#define BN 128
#define BK 32
#define KSTEPS (K_DIM / BK)        // 16
#define TILES_M (M_ROWS / BM)      // 98
#define TILES_N (N_DIM / BN)       // 16
#define NBLK (TILES_M * TILES_N)   // 1568 (divisible by 8)

// ---------------- Kernel 1: residual add + LayerNorm -> bf16 ----------------
__global__ __launch_bounds__(256) void add_ln_bf16(
    const float* __restrict__ xa, const float* __restrict__ xb,
    const float* __restrict__ gamma, const float* __restrict__ beta,
    bf16_t* __restrict__ xn)
{
    const int wave = threadIdx.x >> 6;
    const int lane = threadIdx.x & 63;
    const int row  = blockIdx.x * 4 + wave;
    const size_t base = (size_t)row * K_DIM + lane * 8;

    float4 a0 = *(const float4*)(xa + base);
    float4 a1 = *(const float4*)(xa + base + 4);
    float4 b0 = *(const float4*)(xb + base);
    float4 b1 = *(const float4*)(xb + base + 4);

    float v[8] = {a0.x + b0.x, a0.y + b0.y, a0.z + b0.z, a0.w + b0.w,
                  a1.x + b1.x, a1.y + b1.y, a1.z + b1.z, a1.w + b1.w};
    float s = 0.f, sq = 0.f;
#pragma unroll
    for (int j = 0; j < 8; ++j) { s += v[j]; sq += v[j] * v[j]; }
#pragma unroll
    for (int off = 32; off >= 1; off >>= 1) {
        s  += __shfl_xor(s, off, 64);
        sq += __shfl_xor(sq, off, 64);
    }
    const float mean = s * (1.0f / 512.0f);
    const float var  = sq * (1.0f / 512.0f) - mean * mean;
    const float rstd = rsqrtf(var + 1e-5f);

    float4 g0  = *(const float4*)(gamma + lane * 8);
    float4 g1  = *(const float4*)(gamma + lane * 8 + 4);
    float4 be0 = *(const float4*)(beta  + lane * 8);
    float4 be1 = *(const float4*)(beta  + lane * 8 + 4);
    float g[8]  = {g0.x, g0.y, g0.z, g0.w, g1.x, g1.y, g1.z, g1.w};
    float bt[8] = {be0.x, be0.y, be0.z, be0.w, be1.x, be1.y, be1.z, be1.w};

    bf16x8 o;
#pragma unroll
    for (int j = 0; j < 8; ++j)
        o[j] = (bf16_t)((v[j] - mean) * rstd * g[j] + bt[j]);
    *(bf16x8*)(xn + base) = o;
}

// ---------------- Kernel 2: W [512][2048] f32 -> Wt [2048][512] bf16 --------
__global__ __launch_bounds__(256) void wt_bf16(
    const float* __restrict__ W, bf16_t* __restrict__ Wt)
{
    __shared__ float t[32][33];
    const int bk = blockIdx.x & 15;
    const int bn = blockIdx.x >> 4;
    const int tx = threadIdx.x & 31;
    const int ty = threadIdx.x >> 5;
#pragma unroll
    for (int r = 0; r < 4; ++r) {
        int k = bk * 32 + ty + r * 8;
        t[ty + r * 8][tx] = W[(size_t)k * N_DIM + bn * 32 + tx];
    }
    __syncthreads();
#pragma unroll
    for (int r = 0; r < 4; ++r) {
        int n = bn * 32 + ty + r * 8;
        Wt[(size_t)n * K_DIM + bk * 32 + tx] = (bf16_t)t[tx][ty + r * 8];
    }
}

// ---------------- Kernel 3: bf16 MFMA GEMM + bias + exact GELU --------------
__device__ __forceinline__ void gload_lds16(const bf16_t* g, bf16_t* l) {
    __builtin_amdgcn_global_load_lds(
        (const __attribute__((address_space(1))) void*)g,
        (__attribute__((address_space(3))) void*)l, 16, 0, 0);
}

// Branchless exact-GELU: erf via Abramowitz-Stegun 7.1.26 (|err| < ~2e-7)
__device__ __forceinline__ float gelu_f(float x) {
    const float y = fabsf(x) * 0.70710678118654752f;
    const float t = __builtin_amdgcn_rcpf(__builtin_fmaf(0.3275911f, y, 1.0f));
    float p = __builtin_fmaf(1.061405429f, t, -1.453152027f);
    p = __builtin_fmaf(p, t, 1.421413741f);
    p = __builtin_fmaf(p, t, -0.284496736f);
    p = __builtin_fmaf(p, t, 0.254829592f);
    p = p * t;
    const float e = __expf(-y * y);
    float er = __builtin_fmaf(-p, e, 1.0f);   // erf(|x|/sqrt2)
    er = __builtin_copysignf(er, x);
    return 0.5f * x * (1.0f + er);
}

// 128x128 tile, 4 waves, BK=32, 3-slot LDS (48 KB, 3 blocks/CU), with
// REGISTER FRAGMENT READ-AHEAD: step t+1's ds_reads issue BEFORE step t's
// MFMA cluster, so the LDS burst runs under the matrix pipe instead of
// serializing in front of it (the invariant all 7 prior variants shared).
// Per-step discipline (1 barrier, hazard-audited):
//  1. stage tile t+2 -> slot (t+2)%3   [slot's old reads drained by ALL
//     waves at their step t-1 item 2, certified by barrier t-1]
//  2. lgkmcnt(0): my step-t frag reads (issued step t-1) complete
//  3. vmcnt(4): tile t+1 staging drained; item-1's 4 stay in flight
//  4. s_barrier (+sched_barrier: pin reads below) — publication point
//  5. read-ahead step t+1 fragments from slot (t+1)%3
//  6. setprio + 16 MFMA on frag[t&1]
// Swizzle (R5/R11-proven, rule #21 both-sides): write gsrc=(lane&3)^((lane>>3)&3)
// on per-lane global source; read slot j^((row>>1)&3).
__global__ __launch_bounds__(256, 3) void gemm_bias_gelu(
    const bf16_t* __restrict__ A,   // [M_ROWS][K_DIM] bf16
    const bf16_t* __restrict__ Bt,  // [N_DIM][K_DIM]  bf16 (W^T)
    const float* __restrict__ bias, // [N_DIM]
    float* __restrict__ out)        // [M_ROWS][N_DIM] f32
{
    __shared__ bf16_t As[3][BM * BK];   // 3 x 8 KB
    __shared__ bf16_t Bs[3][BN * BK];   // 3 x 8 KB -> 48 KB total

    const int bid = blockIdx.x;
    const int wg  = (bid & 7) * (NBLK / 8) + (bid >> 3);  // XCD-chunked, bijective
    const int tm  = wg >> 4;
    const int tn  = wg & 15;            // tn-fast: B stripe stays L2-hot

    const int tid  = threadIdx.x;
    const int wave = tid >> 6;
    const int lane = tid & 63;
    const int wr = wave >> 1;
    const int wc = wave & 1;

    const bf16_t* Ab = A  + (size_t)tm * BM * K_DIM;
    const bf16_t* Bb = Bt + (size_t)tn * BN * K_DIM;

    // staging: seg = 16 rows x 32 k = 1024 B = 64 lanes x 16 B
    const int srow = lane >> 2;                       // row within segment
    const int gsrc = (lane & 3) ^ ((lane >> 3) & 3);  // inverse-swizzled chunk

    f32x4 acc[4][4];
#pragma unroll
    for (int m = 0; m < 4; ++m)
#pragma unroll
        for (int n = 0; n < 4; ++n)
            acc[m][n] = (f32x4){0.f, 0.f, 0.f, 0.f};

    auto stage = [&](int buf, int k0) {
#pragma unroll
        for (int c = 0; c < 2; ++c) {
            const int seg = wave * 2 + c;             // 0..7, wave-uniform
            const int row = seg * 16 + srow;
            gload_lds16(Ab + (size_t)row * K_DIM + k0 + gsrc * 8, &As[buf][seg * 512]);
            gload_lds16(Bb + (size_t)row * K_DIM + k0 + gsrc * 8, &Bs[buf][seg * 512]);
        }
    };

    bf16x8 af[2][4], bf[2][4];          // ping-pong fragments (static after unroll)
    auto ldfrag = [&](int pb, int slot) {
        const int j = lane >> 4;                      // 16B k-chunk 0..3
#pragma unroll
        for (int m = 0; m < 4; ++m) {
            const int r = wr * 64 + m * 16 + (lane & 15);
            af[pb][m] = *(const bf16x8*)(&As[slot][r * BK + ((j ^ ((r >> 1) & 3)) << 3)]);
        }
#pragma unroll
        for (int n = 0; n < 4; ++n) {
            const int r = wc * 64 + n * 16 + (lane & 15);
            bf[pb][n] = *(const bf16x8*)(&Bs[slot][r * BK + ((j ^ ((r >> 1) & 3)) << 3)]);
        }
    };

    // prologue: tiles 0,1 staged; slot0 published; step-0 frags read
    stage(0, 0);
    stage(1, BK);
    asm volatile("s_waitcnt vmcnt(4)" ::: "memory");
    __builtin_amdgcn_s_barrier();
    __builtin_amdgcn_sched_barrier(0);
    ldfrag(0, 0);

#pragma unroll
    for (int t = 0; t < KSTEPS; ++t) {
        const int cur = t & 1;

        if (t + 2 < KSTEPS) stage((t + 2) % 3, (t + 2) * BK);   // (1)

        asm volatile("s_waitcnt lgkmcnt(0)" ::: "memory");      // (2)
        __builtin_amdgcn_sched_barrier(0);
        if (t + 2 < KSTEPS)
            asm volatile("s_waitcnt vmcnt(4)" ::: "memory");    // (3)
        else if (t + 1 < KSTEPS)
            asm volatile("s_waitcnt vmcnt(0)" ::: "memory");
        __builtin_amdgcn_s_barrier();                           // (4)
        __builtin_amdgcn_sched_barrier(0);

        if (t + 1 < KSTEPS) ldfrag(cur ^ 1, (t + 1) % 3);       // (5) read-ahead

        __builtin_amdgcn_s_setprio(1);                          // (6)
#pragma unroll
        for (int m = 0; m < 4; ++m)
#pragma unroll
            for (int n = 0; n < 4; ++n)
                acc[m][n] = __builtin_amdgcn_mfma_f32_16x16x32_bf16(
                    af[cur][m], bf[cur][n], acc[m][n], 0, 0, 0);
        __builtin_amdgcn_s_setprio(0);
    }

    // Epilogue: bias + exact GELU, nontemporal stores.
    // C/D layout: col = lane&15, row = (lane>>4)*4 + reg.
    const int rbase = tm * BM + wr * 64;
    const int cbase = tn * BN + wc * 64;
#pragma unroll
    for (int n = 0; n < 4; ++n) {
        const int col = cbase + n * 16 + (lane & 15);
        const float bv = bias[col];
#pragma unroll
        for (int m = 0; m < 4; ++m) {
            const int row0 = rbase + m * 16 + (lane >> 4) * 4;
#pragma unroll
            for (int i = 0; i < 4; ++i) {
                const float x = acc[m][n][i] + bv;
                __builtin_nontemporal_store(gelu_f(x),
                    out + (size_t)(row0 + i) * N_DIM + col);
            }
        }
    }
}

extern "C" void kernel_launch(void* const* d_in, const int* in_sizes, int n_in,
                              void* d_out, int out_size, void* d_ws, size_t ws_size,
                              hipStream_t stream)
{
    const float* x203  = (const float*)d_in[0];
    const float* x217  = (const float*)d_in[1];
    const float* gamma = (const float*)d_in[2];
    const float* beta  = (const float*)d_in[3];
    const float* W     = (const float*)d_in[4];
    const float* bias  = (const float*)d_in[5];
    float* out = (float*)d_out;

    bf16_t* xn = (bf16_t*)d_ws;
    bf16_t* Wt = (bf16_t*)((char*)d_ws + (size_t)M_ROWS * K_DIM * sizeof(bf16_t));

    add_ln_bf16<<<M_ROWS / 4, 256, 0, stream>>>(x203, x217, gamma, beta, xn);
    wt_bf16<<<(K_DIM / 32) * (N_DIM / 32), 256, 0, stream>>>(W, Wt);
    gemm_bias_gelu<<<NBLK, 256, 0, stream>>>(xn, Wt, bias, out);
}

// Round 14
// 66.797 us; speedup vs baseline: 1.3073x; 1.0397x over previous
//
#include <hip/hip_runtime.h>
#include <hip/hip_bf16.h>

typedef __bf16 bf16_t;
typedef __bf16 bf16x8 __attribute__((ext_vector_type(8)));
typedef float  f32x4  __attribute__((ext_vector_type(4)));

#define M_ROWS 12544   // 64*14*14
#define K_DIM  512
#define N_DIM  2048
#define BM 256
#define BN 256
#define BK 64
#define KTILES (K_DIM / BK)        // 4
#define TILES_M (M_ROWS / BM)      // 49
#define TILES_N (N_DIM / BN)       // 8
#define NBLK (TILES_M * TILES_N)   // 392 (divisible by 8)

// ---------------- Kernel 1: residual add + LayerNorm -> bf16 ----------------
__global__ __launch_bounds__(256) void add_ln_bf16(
    const float* __restrict__ xa, const float* __restrict__ xb,
    const float* __restrict__ gamma, const float* __restrict__ beta,
    bf16_t* __restrict__ xn)
{
    const int wave = threadIdx.x >> 6;
    const int lane = threadIdx.x & 63;
    const int row  = blockIdx.x * 4 + wave;
    const size_t base = (size_t)row * K_DIM + lane * 8;

    float4 a0 = *(const float4*)(xa + base);
    float4 a1 = *(const float4*)(xa + base + 4);
    float4 b0 = *(const float4*)(xb + base);
    float4 b1 = *(const float4*)(xb + base + 4);

    float v[8] = {a0.x + b0.x, a0.y + b0.y, a0.z + b0.z, a0.w + b0.w,
                  a1.x + b1.x, a1.y + b1.y, a1.z + b1.z, a1.w + b1.w};
    float s = 0.f, sq = 0.f;
#pragma unroll
    for (int j = 0; j < 8; ++j) { s += v[j]; sq += v[j] * v[j]; }
#pragma unroll
    for (int off = 32; off >= 1; off >>= 1) {
        s  += __shfl_xor(s, off, 64);
        sq += __shfl_xor(sq, off, 64);
    }
    const float mean = s * (1.0f / 512.0f);
    const float var  = sq * (1.0f / 512.0f) - mean * mean;
    const float rstd = rsqrtf(var + 1e-5f);

    float4 g0  = *(const float4*)(gamma + lane * 8);
    float4 g1  = *(const float4*)(gamma + lane * 8 + 4);
    float4 be0 = *(const float4*)(beta  + lane * 8);
    float4 be1 = *(const float4*)(beta  + lane * 8 + 4);
    float g[8]  = {g0.x, g0.y, g0.z, g0.w, g1.x, g1.y, g1.z, g1.w};
    float bt[8] = {be0.x, be0.y, be0.z, be0.w, be1.x, be1.y, be1.z, be1.w};

    bf16x8 o;
#pragma unroll
    for (int j = 0; j < 8; ++j)
        o[j] = (bf16_t)((v[j] - mean) * rstd * g[j] + bt[j]);
    *(bf16x8*)(xn + base) = o;
}

// ---------------- Kernel 2: W [512][2048] f32 -> Wt [2048][512] bf16 --------
__global__ __launch_bounds__(256) void wt_bf16(
    const float* __restrict__ W, bf16_t* __restrict__ Wt)
{
    __shared__ float t[32][33];
    const int bk = blockIdx.x & 15;
    const int bn = blockIdx.x >> 4;
    const int tx = threadIdx.x & 31;
    const int ty = threadIdx.x >> 5;
#pragma unroll
    for (int r = 0; r < 4; ++r) {
        int k = bk * 32 + ty + r * 8;
        t[ty + r * 8][tx] = W[(size_t)k * N_DIM + bn * 32 + tx];
    }
    __syncthreads();
#pragma unroll
    for (int r = 0; r < 4; ++r) {
        int n = bn * 32 + ty + r * 8;
        Wt[(size_t)n * K_DIM + bk * 32 + tx] = (bf16_t)t[tx][ty + r * 8];
    }
}

// ---------------- Kernel 3: m201-style 8-wave 256^2 GEMM + bias + GELU ------
__device__ __forceinline__ void gload_lds16(const bf16_t* g, bf16_t* l) {
    __builtin_amdgcn_global_load_lds(
        (const __attribute__((address_space(1))) void*)g,
        (__attribute__((address_space(3))) void*)l, 16, 0, 0);
}

// Branchless exact-GELU: erf via Abramowitz-Stegun 7.1.26 (|err| < ~2e-7)
__device__ __forceinline__ float gelu_f(float x) {
    const float y = fabsf(x) * 0.70710678118654752f;
    const float t = __builtin_amdgcn_rcpf(__builtin_fmaf(0.3275911f, y, 1.0f));
    float p = __builtin_fmaf(1.061405429f, t, -1.453152027f);
    p = __builtin_fmaf(p, t, 1.421413741f);
    p = __builtin_fmaf(p, t, -0.284496736f);
    p = __builtin_fmaf(p, t, 0.254829592f);
    p = p * t;
    const float e = __expf(-y * y);
    float er = __builtin_fmaf(-p, e, 1.0f);   // erf(|x|/sqrt2)
    er = __builtin_copysignf(er, x);
    return 0.5f * x * (1.0f + er);
}

// Faithful m201 template port (guide §5 / T3+T4) at M=12544,N=2048,K=512:
// 256x256 tile, BK=64, 8 waves (wr=wave>>2 M-half, wc=wave&3 N-quarter),
// LDS = 2 dbuf x 2 halves x [128x64] x {A,B} = 128 KB. 4 phases per K-tile,
// each phase: {ds_read subtile || stage ONE half-tile (2 gloads/thread)} ->
// s_barrier -> lgkmcnt(0)+sched_barrier (rule #18) -> setprio(1) -> 16 MFMA
// quadrant -> setprio(0) -> s_barrier. vmcnt(0) ONCE per K-tile at end of
// ph4 (publication point). Quadrant snake q0(m0-3,n0-1) q1(m0-3,n2-3)
// q2(m4-7,n2-3) q3(m4-7,n0-1); B-frags live across phases -> 24 reads /
// 64 MFMA per K-tile per wave. XOR swizzle chunk^(row&7) both sides
// (rule #21): inverse on per-lane global source, forward on ds_read.
// Hazard audit: each LDS half re-staged >=2 barriers after its last
// reader's lgkmcnt(0); cross-wave gload visibility certified by per-wave
// vmcnt(0) + barrier before any wave reads the new tile.
__global__ __launch_bounds__(512) void gemm_bias_gelu(
    const bf16_t* __restrict__ A,   // [M_ROWS][K_DIM] bf16
    const bf16_t* __restrict__ Bt,  // [N_DIM][K_DIM]  bf16 (W^T)
    const float* __restrict__ bias, // [N_DIM]
    float* __restrict__ out)        // [M_ROWS][N_DIM] f32
{
    __shared__ bf16_t As[2][2][128 * 64];   // [dbuf][half][rows x k] 64 KB
    __shared__ bf16_t Bs[2][2][128 * 64];   // 64 KB -> 128 KB total

    const int bid = blockIdx.x;
    const int wg  = (bid & 7) * (NBLK / 8) + (bid >> 3);  // XCD-chunked, bijective
    const int tm  = wg >> 3;            // 0..48
    const int tn  = wg & 7;             // 0..7 (tn-fast: B 2 MB stays L2-hot)

    const int tid  = threadIdx.x;
    const int wave = tid >> 6;          // 0..7
    const int lane = tid & 63;
    const int wr = wave >> 2;           // 0..1 : reads A-half wr only
    const int wc = wave & 3;            // 0..3 : reads B-half wc>>1 only

    const bf16_t* Ab = A  + (size_t)tm * BM * K_DIM;
    const bf16_t* Bb = Bt + (size_t)tn * BN * K_DIM;

    // staging: half-tile = 128 rows x 64 k = 16 KB = 512 thr x 32 B
    // seg = 8 rows; each wave stages segs wave*2, wave*2+1 of the half.
    const int srow = lane >> 3;                 // 0..7 row within segment
    const int jsrc = (lane & 7) ^ srow;         // inverse-swizzled 16B chunk

    // stage ONE half-tile (2 gloads/thread). mat: 0=A, 1=B. h: 0/1.
    auto stage_half = [&](int buf, int k0, int mat, int h) {
        const bf16_t* src = mat ? Bb : Ab;
        bf16_t* dst = mat ? &Bs[buf][h][0] : &As[buf][h][0];
#pragma unroll
        for (int c = 0; c < 2; ++c) {
            const int seg = wave * 2 + c;               // 0..15
            const int rowh = seg * 8 + srow;            // row within half
            const int grow = h * 128 + rowh;            // row within tile
            gload_lds16(src + (size_t)grow * K_DIM + k0 + jsrc * 8,
                        dst + seg * 512);
        }
    };

    f32x4 acc[8][4];
#pragma unroll
    for (int m = 0; m < 8; ++m)
#pragma unroll
        for (int n = 0; n < 4; ++n)
            acc[m][n] = (f32x4){0.f, 0.f, 0.f, 0.f};

    const int l15 = lane & 15;
    const int jbase = lane >> 4;                        // 0..3

    auto lda = [&](int cur, int m, int kk) -> bf16x8 {  // A row m*16+l15 of half wr
        const int rh = m * 16 + l15;                    // 0..127
        const int j = kk * 4 + jbase;
        return *(const bf16x8*)(&As[cur][wr][rh * 64 + ((j ^ (rh & 7)) << 3)]);
    };
    auto ldb = [&](int cur, int n, int kk) -> bf16x8 {  // B row within half wc>>1
        const int rh = (wc & 1) * 64 + n * 16 + l15;    // 0..127
        const int j = kk * 4 + jbase;
        return *(const bf16x8*)(&Bs[cur][wc >> 1][rh * 64 + ((j ^ (rh & 7)) << 3)]);
    };

    // ---- prologue: tile 0 fully staged (8 gloads/thread), drained, published
    stage_half(0, 0, 0, 0); stage_half(0, 0, 0, 1);
    stage_half(0, 0, 1, 0); stage_half(0, 0, 1, 1);
    asm volatile("s_waitcnt vmcnt(0)" ::: "memory");
    __builtin_amdgcn_s_barrier();

    bf16x8 af[4][2], b01[2][2], b23[2][2];

#pragma unroll
    for (int t = 0; t < KTILES; ++t) {
        const int cur = t & 1;
        const int nxt = cur ^ 1;
        const int kn  = (t + 1) * BK;
        const bool more = (t + 1 < KTILES);

        // ---- phase 1: read A0-3 + B0-1 (12 b128); stage A-half0(t+1)
#pragma unroll
        for (int m = 0; m < 4; ++m)
#pragma unroll
            for (int kk = 0; kk < 2; ++kk) af[m][kk] = lda(cur, m, kk);
#pragma unroll
        for (int n = 0; n < 2; ++n)
#pragma unroll
            for (int kk = 0; kk < 2; ++kk) b01[n][kk] = ldb(cur, n, kk);
        if (more) stage_half(nxt, kn, 0, 0);
        __builtin_amdgcn_s_barrier();
        asm volatile("s_waitcnt lgkmcnt(0)" ::: "memory");
        __builtin_amdgcn_sched_barrier(0);
        __builtin_amdgcn_s_setprio(1);
#pragma unroll
        for (int kk = 0; kk < 2; ++kk)
#pragma unroll
            for (int m = 0; m < 4; ++m)
#pragma unroll
                for (int n = 0; n < 2; ++n)
                    acc[m][n] = __builtin_amdgcn_mfma_f32_16x16x32_bf16(
                        af[m][kk], b01[n][kk], acc[m][n], 0, 0, 0);
        __builtin_amdgcn_s_setprio(0);
        __builtin_amdgcn_s_barrier();

        // ---- phase 2: read B2-3 (4 b128); stage A-half1(t+1)
#pragma unroll
        for (int n = 0; n < 2; ++n)
#pragma unroll
            for (int kk = 0; kk < 2; ++kk) b23[n][kk] = ldb(cur, n + 2, kk);
        if (more) stage_half(nxt, kn, 0, 1);
        __builtin_amdgcn_s_barrier();
        asm volatile("s_waitcnt lgkmcnt(0)" ::: "memory");
        __builtin_amdgcn_sched_barrier(0);
        __builtin_amdgcn_s_setprio(1);
#pragma unroll
        for (int kk = 0; kk < 2; ++kk)
#pragma unroll
            for (int m = 0; m < 4; ++m)
#pragma unroll
                for (int n = 0; n < 2; ++n)
                    acc[m][n + 2] = __builtin_amdgcn_mfma_f32_16x16x32_bf16(
                        af[m][kk], b23[n][kk], acc[m][n + 2], 0, 0, 0);
        __builtin_amdgcn_s_setprio(0);
        __builtin_amdgcn_s_barrier();

        // ---- phase 3: read A4-7 (8 b128, af regs reused); stage B-half0(t+1)
#pragma unroll
        for (int m = 0; m < 4; ++m)
#pragma unroll
            for (int kk = 0; kk < 2; ++kk) af[m][kk] = lda(cur, m + 4, kk);
        if (more) stage_half(nxt, kn, 1, 0);
        __builtin_amdgcn_s_barrier();
        asm volatile("s_waitcnt lgkmcnt(0)" ::: "memory");
        __builtin_amdgcn_sched_barrier(0);
        __builtin_amdgcn_s_setprio(1);
#pragma unroll
        for (int kk = 0; kk < 2; ++kk)
#pragma unroll
            for (int m = 0; m < 4; ++m)
#pragma unroll
                for (int n = 0; n < 2; ++n)
                    acc[m + 4][n + 2] = __builtin_amdgcn_mfma_f32_16x16x32_bf16(
                        af[m][kk], b23[n][kk], acc[m + 4][n + 2], 0, 0, 0);
        __builtin_amdgcn_s_setprio(0);
        __builtin_amdgcn_s_barrier();

        // ---- phase 4: no reads; stage B-half1(t+1); MFMA q3; publish tile t+1
        if (more) stage_half(nxt, kn, 1, 1);
        __builtin_amdgcn_s_setprio(1);
#pragma unroll
        for (int kk = 0; kk < 2; ++kk)
#pragma unroll
            for (int m = 0; m < 4; ++m)
#pragma unroll
                for (int n = 0; n < 2; ++n)
                    acc[m + 4][n] = __builtin_amdgcn_mfma_f32_16x16x32_bf16(
                        af[m][kk], b01[n][kk], acc[m + 4][n], 0, 0, 0);
        __builtin_amdgcn_s_setprio(0);
        if (more) {
            asm volatile("s_waitcnt vmcnt(0)" ::: "memory");  // tile t+1 landed
            __builtin_amdgcn_s_barrier();                     // published
        }
    }

    // Epilogue: bias + exact GELU, nontemporal stores.
    // C/D layout: col = lane&15, row = (lane>>4)*4 + reg.
    const int rbase = tm * BM + wr * 128;
    const int cbase = tn * BN + wc * 64;
#pragma unroll
    for (int n = 0; n < 4; ++n) {
        const int col = cbase + n * 16 + l15;
        const float bv = bias[col];
#pragma unroll
        for (int m = 0; m < 8; ++m) {
            const int row0 = rbase + m * 16 + (lane >> 4) * 4;
#pragma unroll
            for (int i = 0; i < 4; ++i) {
                const float x = acc[m][n][i] + bv;
                __builtin_nontemporal_store(gelu_f(x),
                    out + (size_t)(row0 + i) * N_DIM + col);
            }
        }
    }
}

extern "C" void kernel_launch(void* const* d_in, const int* in_sizes, int n_in,
                              void* d_out, int out_size, void* d_ws, size_t ws_size,
                              hipStream_t stream)
{
    const float* x203  = (const float*)d_in[0];
    const float* x217  = (const float*)d_in[1];
    const float* gamma = (const float*)d_in[2];
    const float* beta  = (const float*)d_in[3];
    const float* W     = (const float*)d_in[4];
    const float* bias  = (const float*)d_in[5];
    float* out = (float*)d_out;

    bf16_t* xn = (bf16_t*)d_ws;
    bf16_t* Wt = (bf16_t*)((char*)d_ws + (size_t)M_ROWS * K_DIM * sizeof(bf16_t));

    add_ln_bf16<<<M_ROWS / 4, 256, 0, stream>>>(x203, x217, gamma, beta, xn);
    wt_bf16<<<(K_DIM / 32) * (N_DIM / 32), 256, 0, stream>>>(W, Wt);
    gemm_bias_gelu<<<NBLK, 512, 0, stream>>>(xn, Wt, bias, out);
}

// Round 15
// 62.881 us; speedup vs baseline: 1.3887x; 1.0623x over previous
//
#include <hip/hip_runtime.h>
#include <hip/hip_bf16.h>

typedef __bf16 bf16_t;
typedef __bf16 bf16x8 __attribute__((ext_vector_type(8)));
typedef float  f32x4  __attribute__((ext_vector_type(4)));

#define M_ROWS 12544   // 64*14*14
#define K_DIM  512
#define N_DIM  2048
#define BM 128
#define BN 128
#define BK 64
#define KSTEPS (K_DIM / BK)        // 8
#define TILES_M (M_ROWS / BM)      // 98
#define TILES_N (N_DIM / BN)       // 16
#define NBLK (TILES_M * TILES_N)   // 1568 (divisible by 8)

// ---------------- Kernel 1: residual add + LayerNorm -> bf16 ----------------
__global__ __launch_bounds__(256) void add_ln_bf16(
    const float* __restrict__ xa, const float* __restrict__ xb,
    const float* __restrict__ gamma, const float* __restrict__ beta,
    bf16_t* __restrict__ xn)
{
    const int wave = threadIdx.x >> 6;
    const int lane = threadIdx.x & 63;
    const int row  = blockIdx.x * 4 + wave;
    const size_t base = (size_t)row * K_DIM + lane * 8;

    float4 a0 = *(const float4*)(xa + base);
    float4 a1 = *(const float4*)(xa + base + 4);
    float4 b0 = *(const float4*)(xb + base);
    float4 b1 = *(const float4*)(xb + base + 4);

    float v[8] = {a0.x + b0.x, a0.y + b0.y, a0.z + b0.z, a0.w + b0.w,
                  a1.x + b1.x, a1.y + b1.y, a1.z + b1.z, a1.w + b1.w};
    float s = 0.f, sq = 0.f;
#pragma unroll
    for (int j = 0; j < 8; ++j) { s += v[j]; sq += v[j] * v[j]; }
#pragma unroll
    for (int off = 32; off >= 1; off >>= 1) {
        s  += __shfl_xor(s, off, 64);
        sq += __shfl_xor(sq, off, 64);
    }
    const float mean = s * (1.0f / 512.0f);
    const float var  = sq * (1.0f / 512.0f) - mean * mean;
    const float rstd = rsqrtf(var + 1e-5f);

    float4 g0  = *(const float4*)(gamma + lane * 8);
    float4 g1  = *(const float4*)(gamma + lane * 8 + 4);
    float4 be0 = *(const float4*)(beta  + lane * 8);
    float4 be1 = *(const float4*)(beta  + lane * 8 + 4);
    float g[8]  = {g0.x, g0.y, g0.z, g0.w, g1.x, g1.y, g1.z, g1.w};
    float bt[8] = {be0.x, be0.y, be0.z, be0.w, be1.x, be1.y, be1.z, be1.w};

    bf16x8 o;
#pragma unroll
    for (int j = 0; j < 8; ++j)
        o[j] = (bf16_t)((v[j] - mean) * rstd * g[j] + bt[j]);
    *(bf16x8*)(xn + base) = o;
}

// ---------------- Kernel 2: W [512][2048] f32 -> Wt [2048][512] bf16 --------
__global__ __launch_bounds__(256) void wt_bf16(
    const float* __restrict__ W, bf16_t* __restrict__ Wt)
{
    __shared__ float t[32][33];
    const int bk = blockIdx.x & 15;
    const int bn = blockIdx.x >> 4;
    const int tx = threadIdx.x & 31;
    const int ty = threadIdx.x >> 5;
#pragma unroll
    for (int r = 0; r < 4; ++r) {
        int k = bk * 32 + ty + r * 8;
        t[ty + r * 8][tx] = W[(size_t)k * N_DIM + bn * 32 + tx];
    }
    __syncthreads();
#pragma unroll
    for (int r = 0; r < 4; ++r) {
        int n = bn * 32 + ty + r * 8;
        Wt[(size_t)n * K_DIM + bk * 32 + tx] = (bf16_t)t[tx][ty + r * 8];
    }
}

// ---------------- Kernel 3: bf16 MFMA GEMM + bias + exact GELU --------------
__device__ __forceinline__ void gload_lds16(const bf16_t* g, bf16_t* l) {
    __builtin_amdgcn_global_load_lds(
        (const __attribute__((address_space(1))) void*)g,
        (__attribute__((address_space(3))) void*)l, 16, 0, 0);
}

// Branchless exact-GELU: erf via Abramowitz-Stegun 7.1.26 (|err| < ~2e-7)
__device__ __forceinline__ float gelu_f(float x) {
    const float y = fabsf(x) * 0.70710678118654752f;
    const float t = __builtin_amdgcn_rcpf(__builtin_fmaf(0.3275911f, y, 1.0f));
    float p = __builtin_fmaf(1.061405429f, t, -1.453152027f);
    p = __builtin_fmaf(p, t, 1.421413741f);
    p = __builtin_fmaf(p, t, -0.284496736f);
    p = __builtin_fmaf(p, t, 0.254829592f);
    p = p * t;
    const float e = __expf(-y * y);
    float er = __builtin_fmaf(-p, e, 1.0f);   // erf(|x|/sqrt2)
    er = __builtin_copysignf(er, x);
    return 0.5f * x * (1.0f + er);
}

// EXACT R4 base (58.7 us: 128^2 tile, 4 waves, BK=64, dbuf LDS, vmcnt(8),
// both-sides XOR swizzle) with ONE change: the epilogue. Old epilogue =
// 16 scalar f32 stores/thread in MFMA C-layout (4-rows x 16-cols scatter,
// 256B/wave-instr) — the single pattern shared by all nine 58-66 us
// variants; theory: the scattered-dword store path caps ~2.2 TB/s and
// floors the kernel at ~50 us for the 103 MB output. New epilogue:
// per-wave LDS transpose (padded stride, 2-way bank alias = free) then
// dwordx4 stores, 4 rows x 256 B contiguous per instruction — the same
// pattern class as the 7 TB/s fill kernel.
__global__ __launch_bounds__(256) void gemm_bias_gelu(
    const bf16_t* __restrict__ A,   // [M_ROWS][K_DIM] bf16
    const bf16_t* __restrict__ Bt,  // [N_DIM][K_DIM]  bf16 (W^T)
    const float* __restrict__ bias, // [N_DIM]
    float* __restrict__ out)        // [M_ROWS][N_DIM] f32
{
    __shared__ bf16_t As[2][BM * BK];   // 2 x 16 KB
    __shared__ bf16_t Bs[2][BN * BK];   // 2 x 16 KB -> 64 KB total

    const int bid = blockIdx.x;
    const int wg  = (bid & 7) * (NBLK / 8) + (bid >> 3);  // XCD-chunked, bijective
    const int tm  = wg >> 4;
    const int tn  = wg & 15;            // tn-fast: B stripe stays L2-hot

    const int tid  = threadIdx.x;
    const int wave = tid >> 6;
    const int lane = tid & 63;
    const int wr = wave >> 1;
    const int wc = wave & 1;

    const bf16_t* Ab = A  + (size_t)tm * BM * K_DIM;
    const bf16_t* Bb = Bt + (size_t)tn * BN * K_DIM;

    // staging: seg = 8 rows x 64 k = 1024 B = 64 lanes x 16 B
    const int srow = lane >> 3;                 // 0..7 row within segment
    const int jsrc = (lane & 7) ^ srow;         // inverse-swizzled 16B chunk

    f32x4 acc[4][4];
#pragma unroll
    for (int m = 0; m < 4; ++m)
#pragma unroll
        for (int n = 0; n < 4; ++n)
            acc[m][n] = (f32x4){0.f, 0.f, 0.f, 0.f};

    auto stage = [&](int buf, int k0) {
#pragma unroll
        for (int c = 0; c < 4; ++c) {
            const int seg = wave * 4 + c;       // wave-uniform LDS base
            const int row = seg * 8 + srow;
            gload_lds16(Ab + (size_t)row * K_DIM + k0 + jsrc * 8, &As[buf][seg * 512]);
            gload_lds16(Bb + (size_t)row * K_DIM + k0 + jsrc * 8, &Bs[buf][seg * 512]);
        }
    };

    stage(0, 0);   // prologue: 8 loads in flight

#pragma unroll
    for (int t = 0; t < KSTEPS; ++t) {
        const int cur = t & 1;
        if (t < KSTEPS - 1) {
            stage(cur ^ 1, (t + 1) * BK);                    // +8 loads (next tile)
            asm volatile("s_waitcnt vmcnt(8)" ::: "memory"); // tile t landed
        } else {
            asm volatile("s_waitcnt vmcnt(0)" ::: "memory");
        }
        __builtin_amdgcn_s_barrier();

#pragma unroll
        for (int kk = 0; kk < 2; ++kk) {
            bf16x8 af[4], bfr[4];
            const int j = kk * 4 + (lane >> 4);  // 16B k-slot 0..7
#pragma unroll
            for (int m = 0; m < 4; ++m) {
                const int r = wr * 64 + m * 16 + (lane & 15);
                af[m] = *(const bf16x8*)(&As[cur][r * BK + ((j ^ (r & 7)) << 3)]);
            }
#pragma unroll
            for (int n = 0; n < 4; ++n) {
                const int r = wc * 64 + n * 16 + (lane & 15);
                bfr[n] = *(const bf16x8*)(&Bs[cur][r * BK + ((j ^ (r & 7)) << 3)]);
            }
#pragma unroll
            for (int m = 0; m < 4; ++m)
#pragma unroll
                for (int n = 0; n < 4; ++n)
                    acc[m][n] = __builtin_amdgcn_mfma_f32_16x16x32_bf16(
                        af[m], bfr[n], acc[m][n], 0, 0, 0);
        }
        if (t < KSTEPS - 1) __builtin_amdgcn_s_barrier();  // reads done before restage
    }

    // ---- Epilogue: bias + exact GELU, LDS-transpose -> coalesced dwordx4.
    // acc C/D layout: col = lane&15, row = (lane>>4)*4 + reg (m89/m91).
    // Per m-fragment: wave writes 16 rows x 64 cols f32 into per-wave LDS
    // scratch (row stride 68 f32: write pattern 2-way bank alias = free),
    // reads back with lane = (row pair, 16B chunk), stores 4 rows x 256 B
    // contiguous per instruction.
    __syncthreads();   // all waves done with As/Bs fragment reads
    float* sco = ((float*)As) + wave * (16 * 68 + 16);   // 4x4416B < 32 KB

    const int l15 = lane & 15;
    const int rbase = tm * BM + wr * 64;
    const int cbase = tn * BN + wc * 64;

    float bv[4];
#pragma unroll
    for (int n = 0; n < 4; ++n) bv[n] = bias[cbase + n * 16 + l15];

#pragma unroll
    for (int m = 0; m < 4; ++m) {
        // write phase: 16 scalar ds_writes (2-way bank alias)
#pragma unroll
        for (int n = 0; n < 4; ++n) {
#pragma unroll
            for (int i = 0; i < 4; ++i) {
                const int row = (lane >> 4) * 4 + i;         // 0..15
                sco[row * 68 + n * 16 + l15] = gelu_f(acc[m][n][i] + bv[n]);
            }
        }
        // wave-internal ordering: ds ops in-order per wave; fence the compiler
        asm volatile("s_waitcnt lgkmcnt(0)" ::: "memory");
        __builtin_amdgcn_sched_barrier(0);

        // read+store phase: 4 wide stores, each 4 rows x 256 B contiguous
#pragma unroll
        for (int jj = 0; jj < 4; ++jj) {
            const int row = jj * 4 + (lane >> 4);            // 0..15
            const f32x4 v = *(const f32x4*)&sco[row * 68 + l15 * 4];
            __builtin_nontemporal_store(v,
                (f32x4*)(out + (size_t)(rbase + m * 16 + row) * N_DIM
                             + cbase + l15 * 4));
        }
        // reads retired before next m overwrites the region
        asm volatile("s_waitcnt lgkmcnt(0)" ::: "memory");
        __builtin_amdgcn_sched_barrier(0);
    }
}

extern "C" void kernel_launch(void* const* d_in, const int* in_sizes, int n_in,
                              void* d_out, int out_size, void* d_ws, size_t ws_size,
                              hipStream_t stream)
{
    const float* x203  = (const float*)d_in[0];
    const float* x217  = (const float*)d_in[1];
    const float* gamma = (const float*)d_in[2];
    const float* beta  = (const float*)d_in[3];
    const float* W     = (const float*)d_in[4];
    const float* bias  = (const float*)d_in[5];
    float* out = (float*)d_out;

    bf16_t* xn = (bf16_t*)d_ws;
    bf16_t* Wt = (bf16_t*)((char*)d_ws + (size_t)M_ROWS * K_DIM * sizeof(bf16_t));

    add_ln_bf16<<<M_ROWS / 4, 256, 0, stream>>>(x203, x217, gamma, beta, xn);
    wt_bf16<<<(K_DIM / 32) * (N_DIM / 32), 256, 0, stream>>>(W, Wt);
    gemm_bias_gelu<<<NBLK, 256, 0, stream>>>(xn, Wt, bias, out);
}